// Round 4
// baseline (61573.517 us; speedup 1.0000x reference)
//
#include <hip/hip_runtime.h>
#include <hip/hip_bf16.h>

#define BB 512
#define SS 512
#define EE 128
#define HH 256
#define VV 128
#define G4H 1024

using bf16 = __bf16;

__device__ __forceinline__ float sigf(float x) { return 1.0f / (1.0f + __expf(-x)); }
__device__ __forceinline__ float tanhf_(float x) {
  float e = __expf(-2.0f * fabsf(x));
  float r = (1.0f - e) / (1.0f + e);
  return x < 0.0f ? -r : r;
}

// ---------------------------------------------------------------------------
// x dtype sniffer: values are 0..127. If x is int64 (LE), every odd 32-bit
// word is 0. If int32, odd words are genuine uniform values (P(all 0) ~ 0).
// flag=1 => int32, flag=0 => int64. flag is pre-zeroed via hipMemsetAsync.
// ---------------------------------------------------------------------------
__global__ void detect_kernel(const int* __restrict__ x, int* __restrict__ flag) {
  const int i = blockIdx.x * 256 + threadIdx.x;   // samples first 4096 words
  if (x[2 * i + 1] != 0) atomicOr(flag, 1);
}

// ---------------------------------------------------------------------------
// table[v][g] = dot(emb[v,:], Wi0[g,:]) + bi0[g] + bh0[g]   (fp32, 128x1024)
// ---------------------------------------------------------------------------
__global__ __launch_bounds__(256)
void table_kernel(const float* __restrict__ emb, const float* __restrict__ Wi,
                  const float* __restrict__ bi, const float* __restrict__ bh,
                  float* __restrict__ table) {
  const int g = blockIdx.x * 256 + threadIdx.x;  // 0..1023
  const int v = blockIdx.y;                      // 0..127
  float s = bi[g] + bh[g];
  const float* er = emb + v * EE;
  const float* wr = Wi + (size_t)g * EE;
  #pragma unroll 4
  for (int e = 0; e < EE; ++e) s += er[e] * wr[e];
  table[v * G4H + g] = s;
}

// ---------------------------------------------------------------------------
// LSTM layer 0, pure fp32 VALU. 128 WGs x 256 thr; WG owns 4 batch rows.
// Thread owns hidden col = tid; its 4 gate rows are q*H + tid.
// h state double-buffered in LDS; c in VGPRs. One barrier per step.
// ---------------------------------------------------------------------------
__global__ __launch_bounds__(256)
void rec0_kernel(const int* __restrict__ x, const int* __restrict__ flagp,
                 const float* __restrict__ Wh, const float* __restrict__ table,
                 bf16* __restrict__ h1) {
  __shared__ float hl[2][4][HH];
  const int tid = threadIdx.x;
  const int b0 = blockIdx.x * 4;
  const int is32 = *flagp;
  float c[4] = {0.f, 0.f, 0.f, 0.f};
  for (int i = tid; i < 4 * HH; i += 256) (&hl[0][0][0])[i] = 0.f;
  __syncthreads();

  for (int t = 0; t < SS; ++t) {
    const int p = t & 1;
    float acc[4][4];
    #pragma unroll
    for (int b = 0; b < 4; ++b) {
      const long xi = (long)(b0 + b) * SS + t;
      const int idx = x[is32 ? xi : 2 * xi] & 127;   // clamp = OOB insurance
      #pragma unroll
      for (int q = 0; q < 4; ++q) acc[b][q] = table[idx * G4H + q * HH + tid];
    }
    #pragma unroll 4
    for (int kc = 0; kc < HH / 4; ++kc) {
      float4 w[4];
      #pragma unroll
      for (int q = 0; q < 4; ++q)
        w[q] = *(const float4*)(Wh + (size_t)(q * HH + tid) * HH + kc * 4);
      #pragma unroll
      for (int b = 0; b < 4; ++b) {
        const float4 hv = *(const float4*)&hl[p][b][kc * 4];
        #pragma unroll
        for (int q = 0; q < 4; ++q)
          acc[b][q] += hv.x * w[q].x + hv.y * w[q].y + hv.z * w[q].z + hv.w * w[q].w;
      }
    }
    #pragma unroll
    for (int b = 0; b < 4; ++b) {
      const float fg = sigf(acc[b][0]);
      const float ig = sigf(acc[b][1]);
      const float gg = tanhf_(acc[b][2]);
      const float og = sigf(acc[b][3]);
      const float cc = fg * c[b] + ig * gg;
      c[b] = cc;
      const float h = og * tanhf_(cc);
      hl[p ^ 1][b][tid] = h;
      h1[((size_t)(b0 + b) * SS + t) * HH + tid] = (bf16)h;
    }
    __syncthreads();
  }
}

// ---------------------------------------------------------------------------
// LSTM layer 1 with fused input GEMM and fused vocab projection. fp32 output.
// ---------------------------------------------------------------------------
__global__ __launch_bounds__(256)
void rec1_kernel(const bf16* __restrict__ h1,
                 const float* __restrict__ Wi, const float* __restrict__ bi,
                 const float* __restrict__ bh, const float* __restrict__ Wh,
                 const float* __restrict__ Wg, const float* __restrict__ bg,
                 float* __restrict__ out) {
  __shared__ float hl[2][4][HH];   // h2 state
  __shared__ float s1[2][4][HH];   // staged h1_t
  const int tid = threadIdx.x;
  const int b0 = blockIdx.x * 4;
  float c[4] = {0.f, 0.f, 0.f, 0.f};
  float bq[4];
  #pragma unroll
  for (int q = 0; q < 4; ++q) bq[q] = bi[q * HH + tid] + bh[q * HH + tid];

  for (int i = tid; i < 4 * HH; i += 256) (&hl[0][0][0])[i] = 0.f;
  #pragma unroll
  for (int b = 0; b < 4; ++b)
    s1[0][b][tid] = (float)h1[((size_t)(b0 + b) * SS + 0) * HH + tid];
  __syncthreads();

  for (int t = 0; t < SS; ++t) {
    const int p = t & 1;
    float acc[4][4];
    #pragma unroll
    for (int b = 0; b < 4; ++b)
      #pragma unroll
      for (int q = 0; q < 4; ++q) acc[b][q] = bq[q];

    // input contribution: Wi1 . h1_t (from s1[p])
    #pragma unroll 4
    for (int kc = 0; kc < HH / 4; ++kc) {
      float4 w[4];
      #pragma unroll
      for (int q = 0; q < 4; ++q)
        w[q] = *(const float4*)(Wi + (size_t)(q * HH + tid) * HH + kc * 4);
      #pragma unroll
      for (int b = 0; b < 4; ++b) {
        const float4 hv = *(const float4*)&s1[p][b][kc * 4];
        #pragma unroll
        for (int q = 0; q < 4; ++q)
          acc[b][q] += hv.x * w[q].x + hv.y * w[q].y + hv.z * w[q].z + hv.w * w[q].w;
      }
    }
    // recurrent contribution: Wh1 . h2_{t-1} (from hl[p])
    #pragma unroll 4
    for (int kc = 0; kc < HH / 4; ++kc) {
      float4 w[4];
      #pragma unroll
      for (int q = 0; q < 4; ++q)
        w[q] = *(const float4*)(Wh + (size_t)(q * HH + tid) * HH + kc * 4);
      #pragma unroll
      for (int b = 0; b < 4; ++b) {
        const float4 hv = *(const float4*)&hl[p][b][kc * 4];
        #pragma unroll
        for (int q = 0; q < 4; ++q)
          acc[b][q] += hv.x * w[q].x + hv.y * w[q].y + hv.z * w[q].z + hv.w * w[q].w;
      }
    }
    // state update
    #pragma unroll
    for (int b = 0; b < 4; ++b) {
      const float fg = sigf(acc[b][0]);
      const float ig = sigf(acc[b][1]);
      const float gg = tanhf_(acc[b][2]);
      const float og = sigf(acc[b][3]);
      const float cc = fg * c[b] + ig * gg;
      c[b] = cc;
      hl[p ^ 1][b][tid] = og * tanhf_(cc);
    }
    // prefetch h1_{t+1}
    if (t + 1 < SS) {
      #pragma unroll
      for (int b = 0; b < 4; ++b)
        s1[p ^ 1][b][tid] = (float)h1[((size_t)(b0 + b) * SS + (t + 1)) * HH + tid];
    }
    __syncthreads();
    // fused projection for step t: logits = h2_t @ Wg^T + bg  (fp32 out)
    {
      const int v = tid & 127;
      const int bp = tid >> 7;           // 0..1 -> batches {2bp, 2bp+1}
      #pragma unroll
      for (int bb = 0; bb < 2; ++bb) {
        const int b = bp * 2 + bb;
        float s = bg[v];
        #pragma unroll 4
        for (int k = 0; k < HH; k += 4) {
          const float4 wg = *(const float4*)(Wg + (size_t)v * HH + k);
          s += hl[p ^ 1][b][k] * wg.x + hl[p ^ 1][b][k + 1] * wg.y +
               hl[p ^ 1][b][k + 2] * wg.z + hl[p ^ 1][b][k + 3] * wg.w;
        }
        out[((size_t)(b0 + b) * SS + t) * VV + v] = s;
      }
    }
  }
}

extern "C" void kernel_launch(void* const* d_in, const int* in_sizes, int n_in,
                              void* d_out, int out_size, void* d_ws, size_t ws_size,
                              hipStream_t stream) {
  const int*   x   = (const int*)d_in[0];
  const float* emb = (const float*)d_in[1];
  const float* Wi0 = (const float*)d_in[2];
  const float* bi0 = (const float*)d_in[3];
  const float* Wh0 = (const float*)d_in[4];
  const float* bh0 = (const float*)d_in[5];
  const float* Wi1 = (const float*)d_in[6];
  const float* bi1 = (const float*)d_in[7];
  const float* Wh1 = (const float*)d_in[8];
  const float* bh1 = (const float*)d_in[9];
  const float* Wg  = (const float*)d_in[10];
  const float* bg  = (const float*)d_in[11];
  float* out = (float*)d_out;

  // ws layout: [flag 4B ... pad 256B][table fp32 512KB][h1 bf16 128MB]
  char* ws = (char*)d_ws;
  int*   flag  = (int*)ws;
  float* table = (float*)(ws + 256);
  bf16*  h1    = (bf16*)(ws + 256 + (size_t)VV * G4H * sizeof(float));
  const size_t need = 256 + (size_t)VV * G4H * sizeof(float)
                    + (size_t)BB * SS * HH * sizeof(bf16);
  if (ws_size < need) return;   // leaves zeros: diagnostic absmax == max|ref|

  hipMemsetAsync(flag, 0, sizeof(int), stream);
  detect_kernel<<<dim3(8), dim3(256), 0, stream>>>(x, flag);
  table_kernel<<<dim3(4, 128), dim3(256), 0, stream>>>(emb, Wi0, bi0, bh0, table);
  rec0_kernel<<<dim3(BB / 4), dim3(256), 0, stream>>>(x, flag, Wh0, table, h1);
  rec1_kernel<<<dim3(BB / 4), dim3(256), 0, stream>>>(h1, Wi1, bi1, bh1, Wh1, Wg, bg, out);
}

// Round 5
// 4921.501 us; speedup vs baseline: 12.5111x; 12.5111x over previous
//
#include <hip/hip_runtime.h>
#include <hip/hip_bf16.h>

#define BB 512
#define SS 512
#define EE 128
#define HH 256
#define VV 128
#define G4H 1024
#define TSL 64              // rec1 time-slice length
#define NSEG (SS / TSL)     // 8

using bf16 = __bf16;
typedef __attribute__((ext_vector_type(8))) __bf16 bf16x8;
typedef __attribute__((ext_vector_type(4))) float f32x4;

__device__ __forceinline__ float rcpf(float x) { return __builtin_amdgcn_rcpf(x); }
__device__ __forceinline__ float sigf(float x) { return rcpf(1.0f + __expf(-x)); }
__device__ __forceinline__ float tanhf_(float x) {
  float e = __expf(-2.0f * fabsf(x));
  float r = (1.0f - e) * rcpf(1.0f + e);
  return x < 0.0f ? -r : r;
}
__device__ __forceinline__ bf16x8 cvt8(const float* __restrict__ s) {
  bf16x8 f;
  #pragma unroll
  for (int j = 0; j < 8; ++j) f[j] = (bf16)s[j];
  return f;
}

// ---------------------------------------------------------------------------
// x dtype sniffer (validated R4): odd 32-bit words all zero <=> int64.
// ---------------------------------------------------------------------------
__global__ void detect_kernel(const int* __restrict__ x, int* __restrict__ flag) {
  const int i = blockIdx.x * 256 + threadIdx.x;
  if (x[2 * i + 1] != 0) atomicOr(flag, 1);
}

// ---------------------------------------------------------------------------
// table[v][g] = dot(emb[v,:], Wi0[g,:]) + bi0[g] + bh0[g]   (fp32, 128x1024)
// ---------------------------------------------------------------------------
__global__ __launch_bounds__(256)
void table_kernel(const float* __restrict__ emb, const float* __restrict__ Wi,
                  const float* __restrict__ bi, const float* __restrict__ bh,
                  float* __restrict__ table) {
  const int g = blockIdx.x * 256 + threadIdx.x;
  const int v = blockIdx.y;
  float s = bi[g] + bh[g];
  const float* er = emb + v * EE;
  const float* wr = Wi + (size_t)g * EE;
  #pragma unroll 4
  for (int e = 0; e < EE; ++e) s += er[e] * wr[e];
  table[v * G4H + g] = s;
}

// ---------------------------------------------------------------------------
// MFMA recurrence, layer 0. 32 WGs x 512 thr (8 waves, 2/SIMD, 256-VGPR cap).
// Wave w owns hidden cols [32w,32w+32): 4 gates x 2 tiles. f,i,g weights in
// VGPRs (192), o-gate in LDS (128KB). h state fragment-major in LDS (unit
// (k>>5)*64 + batch*4 + ((k>>3)&3), elem k&7 -> contiguous 1KB per kc-read).
// acc C-init = table gather (input GEMM contribution, V=128 lookup).
// ---------------------------------------------------------------------------
__global__ __launch_bounds__(512, 2)
void rec0_kernel(const int* __restrict__ x, const int* __restrict__ flagp,
                 const float* __restrict__ Wh, const float* __restrict__ table,
                 bf16* __restrict__ h1) {
  __shared__ bf16 hbuf[2][4096];     // 2 x 8KB, fragment-major
  __shared__ bf16x8 wlds[8192];      // 128KB o-gate weights
  const int tid = threadIdx.x, w = tid >> 6, l = tid & 63, lg = l >> 4, ln = l & 15;
  const int b0 = blockIdx.x * 16, hb = w * 32;
  const int is32 = *flagp;

  bf16x8 Wf[6][8];
  #pragma unroll
  for (int qj = 0; qj < 6; ++qj) {
    const int n = (qj >> 1) * HH + hb + 16 * (qj & 1) + ln;
    #pragma unroll
    for (int kc = 0; kc < 8; ++kc) Wf[qj][kc] = cvt8(Wh + (size_t)n * HH + kc * 32 + lg * 8);
  }
  #pragma unroll
  for (int j = 0; j < 2; ++j) {
    const int n = 3 * HH + hb + 16 * j + ln;
    #pragma unroll
    for (int kc = 0; kc < 8; ++kc)
      wlds[((w * 2 + j) * 8 + kc) * 64 + ln * 4 + lg] = cvt8(Wh + (size_t)n * HH + kc * 32 + lg * 8);
  }
  { bf16x8 z = {}; ((bf16x8*)hbuf[0])[tid] = z; }
  float c[2][4] = {};
  __syncthreads();

  #pragma unroll 1
  for (int t = 0; t < SS; ++t) {
    const int p = t & 1;
    int goff[4];
    #pragma unroll
    for (int r = 0; r < 4; ++r) {
      const long xi = (long)(b0 + lg * 4 + r) * SS + t;
      goff[r] = (x[is32 ? xi : 2 * xi] & 127) * G4H;
    }
    f32x4 acc[4][2];
    #pragma unroll
    for (int q = 0; q < 4; ++q)
      #pragma unroll
      for (int j = 0; j < 2; ++j) {
        const int col = q * HH + hb + 16 * j + ln;
        #pragma unroll
        for (int r = 0; r < 4; ++r) acc[q][j][r] = table[goff[r] + col];
      }
    #pragma unroll
    for (int kc = 0; kc < 8; ++kc) {
      bf16x8 a = ((const bf16x8*)hbuf[p])[kc * 64 + ln * 4 + lg];
      #pragma unroll
      for (int qj = 0; qj < 6; ++qj)
        acc[qj >> 1][qj & 1] = __builtin_amdgcn_mfma_f32_16x16x32_bf16(
            a, Wf[qj][kc], acc[qj >> 1][qj & 1], 0, 0, 0);
      #pragma unroll
      for (int j = 0; j < 2; ++j) {
        bf16x8 bw = wlds[((w * 2 + j) * 8 + kc) * 64 + ln * 4 + lg];
        acc[3][j] = __builtin_amdgcn_mfma_f32_16x16x32_bf16(a, bw, acc[3][j], 0, 0, 0);
      }
    }
    #pragma unroll
    for (int j = 0; j < 2; ++j)
      #pragma unroll
      for (int r = 0; r < 4; ++r) {
        const float fg = sigf(acc[0][j][r]);
        const float ig = sigf(acc[1][j][r]);
        const float gg = tanhf_(acc[2][j][r]);
        const float og = sigf(acc[3][j][r]);
        const float cc = fg * c[j][r] + ig * gg;
        c[j][r] = cc;
        const bf16 hv = (bf16)(og * tanhf_(cc));
        const int m = lg * 4 + r;
        hbuf[p ^ 1][(w * 64 + m * 4 + 2 * j + (ln >> 3)) * 8 + (ln & 7)] = hv;
        h1[((size_t)(b0 + m) * SS + t) * HH + hb + 16 * j + ln] = hv;
      }
    __syncthreads();
  }
}

// ---------------------------------------------------------------------------
// MFMA recurrence, layer 1, one time-slice [t0, t0+TSL). acc C-init gathered
// from precomputed xg (bf16, includes bi1+bh1). h2 written over h1's rows
// (already consumed by this slice's xg1). c/h state carried via cws / hreg.
// ---------------------------------------------------------------------------
__global__ __launch_bounds__(512, 2)
void rec1_kernel(const bf16* __restrict__ xg, const float* __restrict__ Wh,
                 bf16* __restrict__ hreg, float* __restrict__ cws, int t0) {
  __shared__ bf16 hbuf[2][4096];
  __shared__ bf16x8 wlds[8192];
  const int tid = threadIdx.x, w = tid >> 6, l = tid & 63, lg = l >> 4, ln = l & 15;
  const int b0 = blockIdx.x * 16, hb = w * 32;

  bf16x8 Wf[6][8];
  #pragma unroll
  for (int qj = 0; qj < 6; ++qj) {
    const int n = (qj >> 1) * HH + hb + 16 * (qj & 1) + ln;
    #pragma unroll
    for (int kc = 0; kc < 8; ++kc) Wf[qj][kc] = cvt8(Wh + (size_t)n * HH + kc * 32 + lg * 8);
  }
  #pragma unroll
  for (int j = 0; j < 2; ++j) {
    const int n = 3 * HH + hb + 16 * j + ln;
    #pragma unroll
    for (int kc = 0; kc < 8; ++kc)
      wlds[((w * 2 + j) * 8 + kc) * 64 + ln * 4 + lg] = cvt8(Wh + (size_t)n * HH + kc * 32 + lg * 8);
  }
  float c[2][4];
  if (t0 == 0) {
    #pragma unroll
    for (int j = 0; j < 2; ++j)
      #pragma unroll
      for (int r = 0; r < 4; ++r) c[j][r] = 0.f;
    bf16x8 z = {};
    ((bf16x8*)hbuf[0])[tid] = z;
  } else {
    #pragma unroll
    for (int j = 0; j < 2; ++j)
      #pragma unroll
      for (int r = 0; r < 4; ++r) {
        const int m = lg * 4 + r, col = hb + 16 * j + ln;
        c[j][r] = cws[(size_t)(b0 + m) * HH + col];
        const bf16 hv = hreg[((size_t)(b0 + m) * SS + (t0 - 1)) * HH + col];
        hbuf[0][(w * 64 + m * 4 + 2 * j + (ln >> 3)) * 8 + (ln & 7)] = hv;
      }
  }
  __syncthreads();

  #pragma unroll 1
  for (int tt = 0; tt < TSL; ++tt) {
    const int t = t0 + tt, p = tt & 1;
    f32x4 acc[4][2];
    #pragma unroll
    for (int q = 0; q < 4; ++q)
      #pragma unroll
      for (int j = 0; j < 2; ++j) {
        const int g = q * HH + hb + 16 * j + ln;
        #pragma unroll
        for (int r = 0; r < 4; ++r)
          acc[q][j][r] = (float)xg[((size_t)(b0 + lg * 4 + r) * TSL + tt) * G4H + g];
      }
    #pragma unroll
    for (int kc = 0; kc < 8; ++kc) {
      bf16x8 a = ((const bf16x8*)hbuf[p])[kc * 64 + ln * 4 + lg];
      #pragma unroll
      for (int qj = 0; qj < 6; ++qj)
        acc[qj >> 1][qj & 1] = __builtin_amdgcn_mfma_f32_16x16x32_bf16(
            a, Wf[qj][kc], acc[qj >> 1][qj & 1], 0, 0, 0);
      #pragma unroll
      for (int j = 0; j < 2; ++j) {
        bf16x8 bw = wlds[((w * 2 + j) * 8 + kc) * 64 + ln * 4 + lg];
        acc[3][j] = __builtin_amdgcn_mfma_f32_16x16x32_bf16(a, bw, acc[3][j], 0, 0, 0);
      }
    }
    #pragma unroll
    for (int j = 0; j < 2; ++j)
      #pragma unroll
      for (int r = 0; r < 4; ++r) {
        const float fg = sigf(acc[0][j][r]);
        const float ig = sigf(acc[1][j][r]);
        const float gg = tanhf_(acc[2][j][r]);
        const float og = sigf(acc[3][j][r]);
        const float cc = fg * c[j][r] + ig * gg;
        c[j][r] = cc;
        const bf16 hv = (bf16)(og * tanhf_(cc));
        const int m = lg * 4 + r;
        hbuf[p ^ 1][(w * 64 + m * 4 + 2 * j + (ln >> 3)) * 8 + (ln & 7)] = hv;
        hreg[((size_t)(b0 + m) * SS + t) * HH + hb + 16 * j + ln] = hv;
      }
    __syncthreads();
  }
  #pragma unroll
  for (int j = 0; j < 2; ++j)
    #pragma unroll
    for (int r = 0; r < 4; ++r)
      cws[(size_t)(b0 + lg * 4 + r) * HH + hb + 16 * j + ln] = c[j][r];
}

// ---------------------------------------------------------------------------
// xg[b][tt][g] = h1[b][t0+tt][:] . Wi1[g][:] + bi1[g] + bh1[g]  (bf16)
// One M-tile (64 rows) == one batch's full 64-step slice (contiguous in h1).
// ---------------------------------------------------------------------------
__global__ __launch_bounds__(256)
void xg1_kernel(const bf16* __restrict__ h1, const float* __restrict__ Wi,
                const float* __restrict__ bi, const float* __restrict__ bh,
                bf16* __restrict__ xg, int t0) {
  constexpr int AST = HH + 8;
  __shared__ __align__(16) bf16 alds[64 * AST];
  __shared__ __align__(16) bf16 blds[64 * AST];
  const int tid = threadIdx.x, w = tid >> 6, l = tid & 63, lg = l >> 4, ln = l & 15;
  const int R0 = blockIdx.x * 64;        // slice row base; batch b = R0>>6
  const int nt0 = blockIdx.y * 64;
  {
    const int row = tid >> 2, seg = tid & 3;
    const bf16* asrc = h1 + ((size_t)(R0 >> 6) * SS + t0 + row) * HH + seg * 64;
    bf16* adst = &alds[row * AST + seg * 64];
    #pragma unroll
    for (int k = 0; k < 8; ++k) *(uint4*)(adst + k * 8) = *(const uint4*)(asrc + k * 8);
    const float* bsrc = Wi + (size_t)(nt0 + row) * HH + seg * 64;
    bf16* bdst = &blds[row * AST + seg * 64];
    #pragma unroll
    for (int k = 0; k < 8; ++k) *(bf16x8*)(bdst + k * 8) = cvt8(bsrc + k * 8);
  }
  __syncthreads();
  f32x4 acc[4] = {};
  #pragma unroll
  for (int kc = 0; kc < 8; ++kc) {
    bf16x8 b = *(const bf16x8*)&blds[(w * 16 + ln) * AST + kc * 32 + lg * 8];
    #pragma unroll
    for (int mt = 0; mt < 4; ++mt) {
      bf16x8 a = *(const bf16x8*)&alds[(mt * 16 + ln) * AST + kc * 32 + lg * 8];
      acc[mt] = __builtin_amdgcn_mfma_f32_16x16x32_bf16(a, b, acc[mt], 0, 0, 0);
    }
  }
  const int n = nt0 + w * 16 + ln;
  const float bias = bi[n] + bh[n];
  #pragma unroll
  for (int mt = 0; mt < 4; ++mt)
    #pragma unroll
    for (int r = 0; r < 4; ++r)
      xg[((size_t)R0 + mt * 16 + lg * 4 + r) * G4H + n] = (bf16)(acc[mt][r] + bias);
}

// ---------------------------------------------------------------------------
// logits = h2 @ Wg^T + bg  (fp32 out).
// ---------------------------------------------------------------------------
__global__ __launch_bounds__(256)
void proj_kernel(const bf16* __restrict__ h2, const float* __restrict__ Wg,
                 const float* __restrict__ bg, float* __restrict__ out) {
  constexpr int AST = HH + 8;
  __shared__ __align__(16) bf16 alds[64 * AST];
  __shared__ __align__(16) bf16 blds[64 * AST];
  const int tid = threadIdx.x, w = tid >> 6, l = tid & 63, lg = l >> 4, ln = l & 15;
  const size_t mt0 = (size_t)blockIdx.x * 64;
  const int nt0 = blockIdx.y * 64;
  {
    const int row = tid >> 2, seg = tid & 3;
    const bf16* asrc = h2 + (mt0 + row) * HH + seg * 64;
    bf16* adst = &alds[row * AST + seg * 64];
    #pragma unroll
    for (int k = 0; k < 8; ++k) *(uint4*)(adst + k * 8) = *(const uint4*)(asrc + k * 8);
    const float* bsrc = Wg + (size_t)(nt0 + row) * HH + seg * 64;
    bf16* bdst = &blds[row * AST + seg * 64];
    #pragma unroll
    for (int k = 0; k < 8; ++k) *(bf16x8*)(bdst + k * 8) = cvt8(bsrc + k * 8);
  }
  __syncthreads();
  f32x4 acc[4] = {};
  #pragma unroll
  for (int kc = 0; kc < 8; ++kc) {
    bf16x8 b = *(const bf16x8*)&blds[(w * 16 + ln) * AST + kc * 32 + lg * 8];
    #pragma unroll
    for (int mt = 0; mt < 4; ++mt) {
      bf16x8 a = *(const bf16x8*)&alds[(mt * 16 + ln) * AST + kc * 32 + lg * 8];
      acc[mt] = __builtin_amdgcn_mfma_f32_16x16x32_bf16(a, b, acc[mt], 0, 0, 0);
    }
  }
  const int n = nt0 + w * 16 + ln;
  const float bias = bg[n];
  #pragma unroll
  for (int mt = 0; mt < 4; ++mt)
    #pragma unroll
    for (int r = 0; r < 4; ++r)
      out[(mt0 + mt * 16 + lg * 4 + r) * VV + n] = acc[mt][r] + bias;
}

extern "C" void kernel_launch(void* const* d_in, const int* in_sizes, int n_in,
                              void* d_out, int out_size, void* d_ws, size_t ws_size,
                              hipStream_t stream) {
  const int*   x   = (const int*)d_in[0];
  const float* emb = (const float*)d_in[1];
  const float* Wi0 = (const float*)d_in[2];
  const float* bi0 = (const float*)d_in[3];
  const float* Wh0 = (const float*)d_in[4];
  const float* bh0 = (const float*)d_in[5];
  const float* Wi1 = (const float*)d_in[6];
  const float* bi1 = (const float*)d_in[7];
  const float* Wh1 = (const float*)d_in[8];
  const float* bh1 = (const float*)d_in[9];
  const float* Wg  = (const float*)d_in[10];
  const float* bg  = (const float*)d_in[11];

  // ws: [flag 256B][table fp32 512KB][hreg bf16 128MB]  == R4's proven need.
  char* ws = (char*)d_ws;
  int*   flag  = (int*)ws;
  float* table = (float*)(ws + 256);
  bf16*  hreg  = (bf16*)(ws + 256 + (size_t)VV * G4H * sizeof(float));
  const size_t need = 256 + (size_t)VV * G4H * sizeof(float)
                    + (size_t)BB * SS * HH * sizeof(bf16);
  if (ws_size < need) return;

  // d_out doubles as scratch until proj: [xg slice 64MB... exactly 67108864B][cws 512KB]
  bf16*  xg  = (bf16*)d_out;                       // BB*TSL*G4H*2 = 67108864 B
  float* cws = (float*)((char*)d_out + (size_t)BB * TSL * G4H * sizeof(bf16));
  float* out = (float*)d_out;

  hipMemsetAsync(flag, 0, sizeof(int), stream);
  detect_kernel<<<dim3(8), dim3(256), 0, stream>>>(x, flag);
  table_kernel<<<dim3(4, 128), dim3(256), 0, stream>>>(emb, Wi0, bi0, bh0, table);
  rec0_kernel<<<dim3(BB / 16), dim3(512), 0, stream>>>(x, flag, Wh0, table, hreg);
  for (int s = 0; s < NSEG; ++s) {
    const int t0 = s * TSL;
    xg1_kernel<<<dim3(BB * TSL / 64, 16), dim3(256), 0, stream>>>(hreg, Wi1, bi1, bh1, xg, t0);
    rec1_kernel<<<dim3(BB / 16), dim3(512), 0, stream>>>(xg, Wh1, hreg, cws, t0);
  }
  proj_kernel<<<dim3(BB * SS / 64, VV / 64), dim3(256), 0, stream>>>(hreg, Wg, bg, out);
}